// Round 1
// baseline (523.064 us; speedup 1.0000x reference)
//
#include <hip/hip_runtime.h>

#define IMG_H 720
#define IMG_W 1280
#define FX_C 800.0f
#define FY_C 800.0f
#define CX_C 640.0f
#define CY_C 360.0f

// Phase 1: init winner buffer to -1
__global__ void init_winner_kernel(int* __restrict__ winner, int npix) {
    int i = blockIdx.x * blockDim.x + threadIdx.x;
    if (i < npix) winner[i] = -1;
}

// Phase 2: project + atomicMax scatter of point index
__global__ void scatter_kernel(const float* __restrict__ pos,
                               int* __restrict__ winner, int n) {
    int i = blockIdx.x * blockDim.x + threadIdx.x;
    if (i >= n) return;
    float x = pos[3 * i + 0];
    float y = pos[3 * i + 1];
    float z = __fadd_rn(pos[3 * i + 2], 3.0f);
    // IEEE-exact, no FMA contraction: must bit-match numpy so floor() agrees
    float u = __fadd_rn(__fmul_rn(FX_C, __fdiv_rn(x, z)), CX_C);
    float v = __fadd_rn(__fmul_rn(FY_C, __fdiv_rn(y, z)), CY_C);
    if (u >= 0.0f && u < (float)IMG_W && v >= 0.0f && v < (float)IMG_H) {
        int xi = (int)floorf(u);
        int yi = (int)floorf(v);
        int pix = yi * IMG_W + xi;
        atomicMax(&winner[pix], i);
    }
}

// Phase 3: per-pixel resolve — recompute weight for the winner point
__global__ void resolve_kernel(const float* __restrict__ pos,
                               const float* __restrict__ scales,
                               const float* __restrict__ colors,
                               const int* __restrict__ winner,
                               float* __restrict__ out, int npix) {
    int p = blockIdx.x * blockDim.x + threadIdx.x;
    if (p >= npix) return;
    int w = winner[p];
    float cr = 0.0f, cg = 0.0f, cb = 0.0f;
    if (w >= 0) {
        float x = pos[3 * w + 0];
        float y = pos[3 * w + 1];
        float z = __fadd_rn(pos[3 * w + 2], 3.0f);
        float u = __fadd_rn(__fmul_rn(FX_C, __fdiv_rn(x, z)), CX_C);
        float v = __fadd_rn(__fmul_rn(FY_C, __fdiv_rn(y, z)), CY_C);
        float dx = __fsub_rn(u, floorf(u));
        float dy = __fsub_rn(v, floorf(v));
        float rad = __fmul_rn(scales[3 * w], 100.0f);
        float num = __fadd_rn(__fmul_rn(dx, dx), __fmul_rn(dy, dy));
        float den = __fmul_rn(2.0f, __fmul_rn(rad, rad));
        float wgt = expf(-__fdiv_rn(num, den));
        cr = __fmul_rn(colors[3 * w + 0], wgt);
        cg = __fmul_rn(colors[3 * w + 1], wgt);
        cb = __fmul_rn(colors[3 * w + 2], wgt);
    }
    out[3 * p + 0] = cr;
    out[3 * p + 1] = cg;
    out[3 * p + 2] = cb;
}

extern "C" void kernel_launch(void* const* d_in, const int* in_sizes, int n_in,
                              void* d_out, int out_size, void* d_ws, size_t ws_size,
                              hipStream_t stream) {
    // inputs: [0] camera_poses (unused), [1] positions (N*3), [2] scales (N*3), [3] colors (N*3)
    const float* positions = (const float*)d_in[1];
    const float* scales    = (const float*)d_in[2];
    const float* colors    = (const float*)d_in[3];
    float* out = (float*)d_out;
    int n = in_sizes[1] / 3;
    const int npix = IMG_H * IMG_W;

    int* winner = (int*)d_ws;  // npix int32 = ~3.7 MB scratch

    init_winner_kernel<<<(npix + 255) / 256, 256, 0, stream>>>(winner, npix);
    scatter_kernel<<<(n + 255) / 256, 256, 0, stream>>>(positions, winner, n);
    resolve_kernel<<<(npix + 255) / 256, 256, 0, stream>>>(positions, scales, colors,
                                                           winner, out, npix);
}

// Round 2
// 146.207 us; speedup vs baseline: 3.5776x; 3.5776x over previous
//
#include <hip/hip_runtime.h>

#define IMG_H 720
#define IMG_W 1280
#define FX_C 800.0f
#define FY_C 800.0f
#define CX_C 640.0f
#define CY_C 360.0f

// Phase 2: project + atomicMax scatter of point index.
// - Reverse mapping: earliest-dispatched blocks carry the HIGHEST indices so
//   winner[] saturates to near-final values immediately.
// - Test-and-skip: winner[] only grows (atomicMax), so any loaded value is a
//   lower bound on the true current value -> skipping when loaded >= i is safe.
__global__ void scatter_kernel(const float* __restrict__ pos,
                               int* __restrict__ winner, int n) {
    int gid = blockIdx.x * blockDim.x + threadIdx.x;
    if (gid >= n) return;
    int i = n - 1 - gid;  // reverse order: high indices first
    float x = pos[3 * i + 0];
    float y = pos[3 * i + 1];
    float z = __fadd_rn(pos[3 * i + 2], 3.0f);
    // IEEE-exact, no FMA contraction: must bit-match numpy so floor() agrees
    float u = __fadd_rn(__fmul_rn(FX_C, __fdiv_rn(x, z)), CX_C);
    float v = __fadd_rn(__fmul_rn(FY_C, __fdiv_rn(y, z)), CY_C);
    if (u >= 0.0f && u < (float)IMG_W && v >= 0.0f && v < (float)IMG_H) {
        int xi = (int)floorf(u);
        int yi = (int)floorf(v);
        int pix = yi * IMG_W + xi;
        if (winner[pix] < i)          // cheap cached read; stale value <= true value
            atomicMax(&winner[pix], i);
    }
}

// Phase 3: per-pixel resolve — recompute weight for the winner point
__global__ void resolve_kernel(const float* __restrict__ pos,
                               const float* __restrict__ scales,
                               const float* __restrict__ colors,
                               const int* __restrict__ winner,
                               float* __restrict__ out, int npix) {
    int p = blockIdx.x * blockDim.x + threadIdx.x;
    if (p >= npix) return;
    int w = winner[p];
    float cr = 0.0f, cg = 0.0f, cb = 0.0f;
    if (w >= 0) {
        float x = pos[3 * w + 0];
        float y = pos[3 * w + 1];
        float z = __fadd_rn(pos[3 * w + 2], 3.0f);
        float u = __fadd_rn(__fmul_rn(FX_C, __fdiv_rn(x, z)), CX_C);
        float v = __fadd_rn(__fmul_rn(FY_C, __fdiv_rn(y, z)), CY_C);
        float dx = __fsub_rn(u, floorf(u));
        float dy = __fsub_rn(v, floorf(v));
        float rad = __fmul_rn(scales[3 * w], 100.0f);
        float num = __fadd_rn(__fmul_rn(dx, dx), __fmul_rn(dy, dy));
        float den = __fmul_rn(2.0f, __fmul_rn(rad, rad));
        float wgt = expf(-__fdiv_rn(num, den));
        cr = __fmul_rn(colors[3 * w + 0], wgt);
        cg = __fmul_rn(colors[3 * w + 1], wgt);
        cb = __fmul_rn(colors[3 * w + 2], wgt);
    }
    out[3 * p + 0] = cr;
    out[3 * p + 1] = cg;
    out[3 * p + 2] = cb;
}

extern "C" void kernel_launch(void* const* d_in, const int* in_sizes, int n_in,
                              void* d_out, int out_size, void* d_ws, size_t ws_size,
                              hipStream_t stream) {
    // inputs: [0] camera_poses (unused), [1] positions (N*3), [2] scales (N*3), [3] colors (N*3)
    const float* positions = (const float*)d_in[1];
    const float* scales    = (const float*)d_in[2];
    const float* colors    = (const float*)d_in[3];
    float* out = (float*)d_out;
    int n = in_sizes[1] / 3;
    const int npix = IMG_H * IMG_W;

    int* winner = (int*)d_ws;  // npix int32 = ~3.7 MB scratch

    // init winner to -1 (0xFFFFFFFF); memsetAsync is graph-capture safe
    hipMemsetAsync(winner, 0xFF, (size_t)npix * sizeof(int), stream);
    scatter_kernel<<<(n + 255) / 256, 256, 0, stream>>>(positions, winner, n);
    resolve_kernel<<<(npix + 255) / 256, 256, 0, stream>>>(positions, scales, colors,
                                                           winner, out, npix);
}